// Round 7
// baseline (1528.912 us; speedup 1.0000x reference)
//
#include <hip/hip_runtime.h>

#define NU 80000
#define NI 40000
#define DD 128
#define NNZ_E 2000000
#define EPSN 1e-12f
#define BWROWS 256
#define NBU 313   // ceil(NU/256)
#define NBI 157   // ceil(NI/256)
#define NBPAD 320
#define BSTRIDE 336
#define BIN_E 8192
#define S2CAP 16384
#define NREP 4    // colsum atomic shards

struct EdgePtrs { const int* rows[4]; const int* cols[4]; const float* vals[4]; };

struct GAll {
  const int* rp[2][4];
  const int2* pairs[2][4];
  const unsigned short* xt[2][4];
  float* out[2][4];
  float* meanb[2];
  float* colsums;
};

struct DupPtrs { float* d[8]; };   // raw u0..u2 (y=0..2), i0..i2 (y=4..6); null else

struct ConvPtrs { const float* src[8]; unsigned short* dst[8]; int n4[8]; };

typedef float f32x4 __attribute__((ext_vector_type(4)));
__device__ inline void nts(float4 v, float4* p) {
  f32x4 w = {v.x, v.y, v.z, v.w};
  __builtin_nontemporal_store(w, (f32x4*)p);
}

__device__ inline unsigned short f2bf(float f) {
  unsigned int u = __float_as_uint(f);
  u += 0x7FFFu + ((u >> 16) & 1u);   // RNE
  return (unsigned short)(u >> 16);
}
__device__ inline float bf2f(unsigned short h) {
  return __uint_as_float((unsigned)h << 16);
}

// -------- fused bf16 conversion of all 8 tables --------
__global__ __launch_bounds__(256) void convA_k(ConvPtrs cp) {
  int y = blockIdx.y;
  const float4* __restrict__ src = (const float4*)cp.src[y];
  ushort4* __restrict__ dst = (ushort4*)cp.dst[y];
  int n4 = cp.n4[y];
  int stride = blockDim.x * gridDim.x;
  for (int i = blockIdx.x * blockDim.x + threadIdx.x; i < n4; i += stride) {
    float4 f = src[i];
    ushort4 h;
    h.x = f2bf(f.x); h.y = f2bf(f.y); h.z = f2bf(f.z); h.w = f2bf(f.w);
    dst[i] = h;
  }
}

__global__ __launch_bounds__(256) void conv_k(const float* __restrict__ src,
                                              unsigned short* __restrict__ dst, int n4) {
  int stride = blockDim.x * gridDim.x;
  for (int i = blockIdx.x * blockDim.x + threadIdx.x; i < n4; i += stride) {
    float4 f = ((const float4*)src)[i];
    ushort4 h;
    h.x = f2bf(f.x); h.y = f2bf(f.y); h.z = f2bf(f.z); h.w = f2bf(f.w);
    ((ushort4*)dst)[i] = h;
  }
}

// -------- bucket-level histogram (LDS-privatized), all behaviors --------
__global__ __launch_bounds__(256) void histB_k(EdgePtrs ep, int* cntA) {
  int b = blockIdx.y;
  const int* __restrict__ rows = ep.rows[b];
  const int* __restrict__ cols = ep.cols[b];
  __shared__ int lh[NBU + NBI];
  for (int i = threadIdx.x; i < NBU + NBI; i += blockDim.x) lh[i] = 0;
  __syncthreads();
  int stride = blockDim.x * gridDim.x;
  for (int e = blockIdx.x * blockDim.x + threadIdx.x; e < NNZ_E; e += stride) {
    atomicAdd(&lh[rows[e] >> 8], 1);
    atomicAdd(&lh[NBU + (cols[e] >> 8)], 1);
  }
  __syncthreads();
  int* cu = cntA + (b * 2 + 0) * NBPAD;
  int* ci = cntA + (b * 2 + 1) * NBPAD;
  for (int i = threadIdx.x; i < NBU + NBI; i += blockDim.x) {
    int v = lh[i];
    if (v) {
      if (i < NBU) atomicAdd(&cu[i], v);
      else atomicAdd(&ci[i - NBU], v);
    }
  }
}

// -------- bucket scan: 8 arrays of <=313 values --------
__global__ __launch_bounds__(512) void scanb_k(const int* cntA, int* baseA, int* gcurA) {
  __shared__ int wsums[9];
  int a = blockIdx.x;              // b*2 + dir
  int dir = a & 1;
  int n = dir ? NBI : NBU;
  const int* cnt = cntA + a * NBPAD;
  int* base = baseA + a * BSTRIDE;
  int* gcur = gcurA + a * NBPAD;
  int t = threadIdx.x, lane = t & 63, w = t >> 6;
  int v = (t < n) ? cnt[t] : 0;
  int s = v;
  #pragma unroll
  for (int off = 1; off < 64; off <<= 1) {
    int x = __shfl_up(s, off);
    if (lane >= off) s += x;
  }
  if (lane == 63) wsums[w] = s;
  __syncthreads();
  if (t == 0) {
    int run = 0;
    for (int k = 0; k < 8; k++) { int x = wsums[k]; wsums[k] = run; run += x; }
    wsums[8] = run;
  }
  __syncthreads();
  int ex = wsums[w] + s - v;
  if (t < n) { base[t] = ex; gcur[t] = ex; }
  if (t == 0) base[n] = wsums[8];
}

// -------- pass 1: counting-sort chunks by bucket, coalesced flush --------
__global__ __launch_bounds__(512) void bin_k(EdgePtrs ep, int b0, int* gcurA, int2* binned) {
  __shared__ int2 stage[BIN_E];     // 64 KB
  __shared__ int lh[NBPAD], lscan[NBPAD], lcur[NBPAD], gpos[NBPAD];
  __shared__ int wsums[9];
  int dir = blockIdx.y, j = blockIdx.z, b = b0 + j;
  int NB = dir ? NBI : NBU;
  const int* __restrict__ dst = dir ? ep.cols[b] : ep.rows[b];
  const int* __restrict__ src = dir ? ep.rows[b] : ep.cols[b];
  const float* __restrict__ vals = ep.vals[b];
  int* gcur = gcurA + (b * 2 + dir) * NBPAD;
  int2* out = binned + ((size_t)j * 2 + dir) * NNZ_E;
  int t = threadIdx.x;
  int e0 = blockIdx.x * BIN_E;
  int nh = min(BIN_E, NNZ_E - e0);
  for (int i = t; i < NBPAD; i += 512) lh[i] = 0;
  __syncthreads();
  for (int i = t; i < nh; i += 512) atomicAdd(&lh[dst[e0 + i] >> 8], 1);
  __syncthreads();
  {
    int lane = t & 63, w = t >> 6;
    int v = (t < NB) ? lh[t] : 0;
    int s = v;
    #pragma unroll
    for (int off = 1; off < 64; off <<= 1) {
      int x = __shfl_up(s, off);
      if (lane >= off) s += x;
    }
    if (lane == 63) wsums[w] = s;
    __syncthreads();
    if (t == 0) {
      int run = 0;
      for (int k = 0; k < 8; k++) { int x = wsums[k]; wsums[k] = run; run += x; }
      wsums[8] = run;
    }
    __syncthreads();
    int ex = wsums[w] + s - v;
    if (t < NB) { lscan[t] = ex; lcur[t] = ex; gpos[t] = atomicAdd(&gcur[t], v); }
  }
  __syncthreads();
  for (int i = t; i < nh; i += 512) {
    int d = dst[e0 + i], s = src[e0 + i];
    int k = d >> 8;
    int pos = atomicAdd(&lcur[k], 1);
    stage[pos] = make_int2(s | ((d & 255) << 17), __float_as_int(vals[e0 + i]));
  }
  __syncthreads();
  int w = t >> 6, lane = t & 63;
  for (int k = w; k < NB; k += 8) {
    int c = lh[k];
    const int2* sp = stage + lscan[k];
    int2* gp = out + gpos[k];
    for (int i = lane; i < c; i += 64) gp[i] = sp[i];
  }
}

// -------- pass 2: per-bucket exact-row sort + CSR row_ptr emission --------
__global__ __launch_bounds__(512) void sort3_k(int* rpU, int* rpI, int b0,
                                               const int* baseA, int2* binned) {
  __shared__ int2 stage[S2CAP];   // 128 KB
  __shared__ int lh[256];
  __shared__ int excl[257];
  __shared__ int lcur[256];
  __shared__ int wsums[5];
  int gb = blockIdx.x;
  int j = gb / (NBU + NBI);
  int r = gb - j * (NBU + NBI);
  int dir = (r >= NBU) ? 1 : 0;
  int k = dir ? (r - NBU) : r;
  int b = b0 + j;
  int n = dir ? NI : NU;
  int* rp = dir ? (rpI + (size_t)b * (NI + 1)) : (rpU + (size_t)b * (NU + 1));
  const int* base = baseA + (b * 2 + dir) * BSTRIDE;
  int2* bb = binned + ((size_t)j * 2 + dir) * NNZ_E;
  int row0 = k << 8;
  int nrows = min(BWROWS, n - row0);
  int base0 = base[k];
  int tot = base[k + 1] - base0;
  int t = threadIdx.x;
  if (t < 256) lh[t] = 0;
  __syncthreads();
  for (int i = t; i < tot; i += 512) atomicAdd(&lh[(bb[base0 + i].x >> 17) & 255], 1);
  __syncthreads();
  int v = 0, s = 0;
  if (t < 256) {
    int lane = t & 63, w = t >> 6;
    v = lh[t]; s = v;
    #pragma unroll
    for (int off = 1; off < 64; off <<= 1) {
      int x = __shfl_up(s, off);
      if (lane >= off) s += x;
    }
    if (lane == 63) wsums[w] = s;
  }
  __syncthreads();
  if (t == 0) {
    int run = 0;
    for (int q = 0; q < 4; q++) { int x = wsums[q]; wsums[q] = run; run += x; }
    wsums[4] = run;
  }
  __syncthreads();
  if (t < 256) {
    int ex = wsums[t >> 6] + s - v;
    excl[t] = ex; lcur[t] = ex;
  }
  if (t == 0) excl[256] = wsums[4];
  __syncthreads();
  if (t <= nrows) rp[row0 + t] = base0 + excl[t];
  for (int i = t; i < tot; i += 512) {
    int2 p = bb[base0 + i];
    int ld = (p.x >> 17) & 255;
    int pos = atomicAdd(&lcur[ld], 1);
    stage[pos] = make_int2(p.x & 0x1FFFF, p.y);
  }
  __syncthreads();
  for (int i = t; i < tot; i += 512) bb[base0 + i] = stage[i];
}

// -------- per-direction fused gather: b-outer, 4 rows/group, 8-edge unroll --------
__global__ __launch_bounds__(256) void gatherD_k(GAll g, int dir) {
  int gid = blockIdx.x * 8 + (threadIdx.x >> 5);
  int lane = threadIdx.x & 31;
  int t = threadIdx.x;
  int r0 = gid * 4;

  float4 z = make_float4(0.f, 0.f, 0.f, 0.f);
  float4 mean[4] = {z, z, z, z};
  float4 sq[4] = {z, z, z, z};

  #pragma unroll
  for (int b = 0; b < 4; b++) {
    const int* __restrict__ rp = g.rp[dir][b];
    const int2* __restrict__ pairs = g.pairs[dir][b];
    const ushort4* __restrict__ x4 = (const ushort4*)g.xt[dir][b];
    float4* __restrict__ outp = (float4*)g.out[dir][b];
    #pragma unroll
    for (int k = 0; k < 4; k++) {
      int r = r0 + k;
      int beg = rp[r], end = rp[r + 1];
      float4 a0 = z, a1 = z;
      int e = beg;
      for (; e + 8 <= end; e += 8) {
        int2 pp[8];
        ushort4 hh[8];
        #pragma unroll
        for (int q = 0; q < 8; q++) pp[q] = pairs[e + q];
        #pragma unroll
        for (int q = 0; q < 8; q++) hh[q] = x4[(size_t)pp[q].x * 32 + lane];
        #pragma unroll
        for (int q = 0; q < 8; q++) {
          float v = __int_as_float(pp[q].y);
          if (q & 1) {
            a1.x += v * bf2f(hh[q].x); a1.y += v * bf2f(hh[q].y);
            a1.z += v * bf2f(hh[q].z); a1.w += v * bf2f(hh[q].w);
          } else {
            a0.x += v * bf2f(hh[q].x); a0.y += v * bf2f(hh[q].y);
            a0.z += v * bf2f(hh[q].z); a0.w += v * bf2f(hh[q].w);
          }
        }
      }
      for (; e < end; e++) {
        int2 p = pairs[e];
        ushort4 h = x4[(size_t)p.x * 32 + lane];
        float v = __int_as_float(p.y);
        a0.x += v * bf2f(h.x); a0.y += v * bf2f(h.y);
        a0.z += v * bf2f(h.z); a0.w += v * bf2f(h.w);
      }
      float4 res = make_float4(a0.x + a1.x, a0.y + a1.y, a0.z + a1.z, a0.w + a1.w);
      nts(res, (float4*)outp + (size_t)r * 32 + lane);
      mean[k].x += res.x; mean[k].y += res.y; mean[k].z += res.z; mean[k].w += res.w;
      sq[b].x += res.x * res.x; sq[b].y += res.y * res.y;
      sq[b].z += res.z * res.z; sq[b].w += res.w * res.w;
    }
  }
  float4* mb = (float4*)g.meanb[dir];
  #pragma unroll
  for (int k = 0; k < 4; k++) {
    float4 m = mean[k];
    m.x *= 0.25f; m.y *= 0.25f; m.z *= 0.25f; m.w *= 0.25f;
    nts(m, mb + (size_t)(r0 + k) * 32 + lane);
  }
  // block-level colsq reduction
  __shared__ float csq[512];
  csq[t] = 0.f; csq[t + 256] = 0.f;
  __syncthreads();
  int cb = lane * 4;
  #pragma unroll
  for (int b = 0; b < 4; b++) {
    atomicAdd(&csq[b * 128 + cb + 0], sq[b].x);
    atomicAdd(&csq[b * 128 + cb + 1], sq[b].y);
    atomicAdd(&csq[b * 128 + cb + 2], sq[b].z);
    atomicAdd(&csq[b * 128 + cb + 3], sq[b].w);
  }
  __syncthreads();
  float* dst = g.colsums + (blockIdx.x & (NREP - 1)) * 1024 + dir * 512;
  atomicAdd(&dst[t], csq[t]);
  atomicAdd(&dst[t + 256], csq[t + 256]);
}

// -------- fallback per-behavior gather (small-ws path) --------
__global__ __launch_bounds__(256) void gather_k(const int* __restrict__ rp, const int2* __restrict__ pairs,
                                                const void* __restrict__ xt, int isbf,
                                                float* __restrict__ out1, float* __restrict__ out2,
                                                int nrows) {
  int gid = blockIdx.x * 8 + (threadIdx.x >> 5);
  int lane = threadIdx.x & 31;
  int tot = gridDim.x * 8;
  for (int r = gid; r < nrows; r += tot) {
    int beg = rp[r], end = rp[r + 1];
    float4 a0 = make_float4(0.f, 0.f, 0.f, 0.f);
    int e = beg;
    if (isbf) {
      const ushort4* __restrict__ x4 = (const ushort4*)xt;
      for (; e < end; e++) {
        int2 p = pairs[e];
        ushort4 h = x4[(size_t)p.x * 32 + lane];
        float v = __int_as_float(p.y);
        a0.x += v * bf2f(h.x); a0.y += v * bf2f(h.y);
        a0.z += v * bf2f(h.z); a0.w += v * bf2f(h.w);
      }
    } else {
      const float4* __restrict__ x4 = (const float4*)xt;
      for (; e < end; e++) {
        int2 p = pairs[e];
        float4 xv = x4[(size_t)p.x * 32 + lane];
        float v = __int_as_float(p.y);
        a0.x += v * xv.x; a0.y += v * xv.y; a0.z += v * xv.z; a0.w += v * xv.w;
      }
    }
    ((float4*)out1)[(size_t)r * 32 + lane] = a0;
    if (out2) ((float4*)out2)[(size_t)r * 32 + lane] = a0;
  }
}

// ---------------- combined GEMM (mean buffers) + sigmoid ----------------
__global__ __launch_bounds__(256) void gemm2_k(const float* __restrict__ meanU,
                                               const float* __restrict__ meanI,
                                               const float* __restrict__ u_w,
                                               const float* __restrict__ i_w,
                                               float* __restrict__ user_out,
                                               float* __restrict__ item_out) {
  __shared__ float wl[DD * DD];
  __shared__ float rl[8][DD];
  int blk = blockIdx.x;
  const float* mean; const float* W; float* outp; int n; int row0;
  if (blk < NU / 64) { mean = meanU; W = u_w; outp = user_out; n = NU; row0 = blk * 64; }
  else { mean = meanI; W = i_w; outp = item_out; n = NI; row0 = (blk - NU / 64) * 64; }
  for (int i = threadIdx.x; i < DD * DD / 4; i += blockDim.x)
    ((float4*)wl)[i] = ((const float4*)W)[i];
  int c = threadIdx.x & 127;
  int g = threadIdx.x >> 7;
  for (int rr = 0; rr < 64; rr += 8) {
    int rbase = row0 + rr;
    __syncthreads();
    for (int i = threadIdx.x; i < 8 * DD; i += blockDim.x) {
      int lr = i >> 7, lc = i & 127;
      int r = rbase + lr;
      rl[lr][lc] = (r < n) ? mean[(size_t)r * DD + lc] : 0.f;
    }
    __syncthreads();
    float acc0 = 0.f, acc1 = 0.f, acc2 = 0.f, acc3 = 0.f;
    #pragma unroll 4
    for (int k = 0; k < DD; k++) {
      float wv = wl[k * DD + c];
      acc0 += rl[g * 4 + 0][k] * wv;
      acc1 += rl[g * 4 + 1][k] * wv;
      acc2 += rl[g * 4 + 2][k] * wv;
      acc3 += rl[g * 4 + 3][k] * wv;
    }
    float accs[4] = {acc0, acc1, acc2, acc3};
    for (int jj = 0; jj < 4; jj++) {
      int r = rbase + g * 4 + jj;
      if (r < n) outp[(size_t)r * DD + c] = 1.f / (1.f + __expf(-accs[jj]));
    }
  }
}

// fallback gemm (reads 4 slices)
__global__ __launch_bounds__(256) void gemm_sig_k(const float* __restrict__ x, size_t sstride,
                                                  const float* __restrict__ W, float* __restrict__ out,
                                                  int n) {
  __shared__ float wl[DD * DD];
  __shared__ float rl[8][DD];
  for (int i = threadIdx.x; i < DD * DD / 4; i += blockDim.x)
    ((float4*)wl)[i] = ((const float4*)W)[i];
  int c = threadIdx.x & 127;
  int g = threadIdx.x >> 7;
  int row0 = blockIdx.x * 64;
  for (int rr = 0; rr < 64; rr += 8) {
    int rbase = row0 + rr;
    __syncthreads();
    for (int i = threadIdx.x; i < 8 * DD; i += blockDim.x) {
      int lr = i >> 7, lc = i & 127;
      int r = rbase + lr;
      float m = 0.f;
      if (r < n) {
        size_t off = (size_t)r * DD + lc;
        m = 0.25f * (x[off] + x[off + sstride] + x[off + 2 * sstride] + x[off + 3 * sstride]);
      }
      rl[lr][lc] = m;
    }
    __syncthreads();
    float acc0 = 0.f, acc1 = 0.f, acc2 = 0.f, acc3 = 0.f;
    #pragma unroll 4
    for (int k = 0; k < DD; k++) {
      float wv = wl[k * DD + c];
      acc0 += rl[g * 4 + 0][k] * wv;
      acc1 += rl[g * 4 + 1][k] * wv;
      acc2 += rl[g * 4 + 2][k] * wv;
      acc3 += rl[g * 4 + 3][k] * wv;
    }
    float accs[4] = {acc0, acc1, acc2, acc3};
    for (int jj = 0; jj < 4; jj++) {
      int r = rbase + g * 4 + jj;
      if (r < n) out[(size_t)r * DD + c] = 1.f / (1.f + __expf(-accs[jj]));
    }
  }
}

// ---------------- colsq (fallback) / inv / scale ----------------
__global__ __launch_bounds__(256) void colsq_k(const float* __restrict__ base, size_t sstride, int n,
                                               float* __restrict__ sums) {
  int b = blockIdx.y;
  const float* x = base + (size_t)b * sstride;
  int c = threadIdx.x & 127;
  int rh = threadIdx.x >> 7;
  float acc = 0.f;
  for (int r = blockIdx.x * 2 + rh; r < n; r += gridDim.x * 2) {
    float v = x[(size_t)r * DD + c];
    acc += v * v;
  }
  __shared__ float red[256];
  red[threadIdx.x] = acc;
  __syncthreads();
  if (threadIdx.x < 128) atomicAdd(&sums[b * DD + threadIdx.x], red[threadIdx.x] + red[threadIdx.x + 128]);
}

__global__ void inv_k(const float* __restrict__ sums, float* __restrict__ inv, int n, int nrep) {
  int i = blockIdx.x * blockDim.x + threadIdx.x;
  if (i < n) {
    float s = 0.f;
    for (int r = 0; r < nrep; r++) s += sums[r * 1024 + i];
    inv[i] = 1.f / fmaxf(sqrtf(s), EPSN);
  }
}

// main path: inv from sharded colsums; writes raw dup + scaled slice (both nt)
__global__ __launch_bounds__(256) void scaleall2_k(float* __restrict__ l2nU, float* __restrict__ l2nI,
                                                   const float* __restrict__ colsums, DupPtrs dp) {
  __shared__ float sinv[DD];
  int y = blockIdx.y;  // 0..3 = U slices, 4..7 = I slices
  int t = threadIdx.x;
  if (t < DD) {
    float s = 0.f;
    #pragma unroll
    for (int rr = 0; rr < NREP; rr++) s += colsums[rr * 1024 + y * DD + t];
    sinv[t] = 1.f / fmaxf(sqrtf(s), EPSN);
  }
  __syncthreads();
  float4* b4;
  size_t slice;
  if (y < 4) { b4 = (float4*)l2nU + (size_t)y * NU * 32; slice = (size_t)NU * 32; }
  else { b4 = (float4*)l2nI + (size_t)(y - 4) * NI * 32; slice = (size_t)NI * 32; }
  float4* dupp = (float4*)dp.d[y];
  const float4* inv4 = (const float4*)sinv;
  size_t stride = (size_t)blockDim.x * gridDim.x;
  for (size_t i = (size_t)blockIdx.x * blockDim.x + threadIdx.x; i < slice; i += stride) {
    float4 s = inv4[i & 31];
    float4 v = b4[i];
    if (dupp) nts(v, dupp + i);
    v.x *= s.x; v.y *= s.y; v.z *= s.z; v.w *= s.w;
    nts(v, b4 + i);
  }
}

// fallback scale (external invs)
__global__ __launch_bounds__(256) void scaleall_k(float* __restrict__ l2nU, float* __restrict__ l2nI,
                                                  const float* __restrict__ invs) {
  int y = blockIdx.y;
  float4* b4;
  size_t slice;
  if (y < 4) { b4 = (float4*)l2nU + (size_t)y * NU * 32; slice = (size_t)NU * 32; }
  else { b4 = (float4*)l2nI + (size_t)(y - 4) * NI * 32; slice = (size_t)NI * 32; }
  const float4* inv4 = (const float4*)invs + (size_t)y * 32;
  size_t stride = (size_t)blockDim.x * gridDim.x;
  for (size_t i = (size_t)blockIdx.x * blockDim.x + threadIdx.x; i < slice; i += stride) {
    float4 s = inv4[i & 31];
    float4 v = b4[i];
    v.x *= s.x; v.y *= s.y; v.z *= s.z; v.w *= s.w;
    b4[i] = v;
  }
}

// ---------------- host ----------------
extern "C" void kernel_launch(void* const* d_in, const int* in_sizes, int n_in,
                              void* d_out, int out_size, void* d_ws, size_t ws_size,
                              hipStream_t stream) {
  const float* user_emb = (const float*)d_in[0];
  const float* item_emb = (const float*)d_in[1];
  const float* uu[4] = {(const float*)d_in[2], (const float*)d_in[4], (const float*)d_in[6], user_emb};
  const float* ii[4] = {(const float*)d_in[3], (const float*)d_in[5], (const float*)d_in[7], item_emb};
  const float* u_w = (const float*)d_in[8];
  const float* i_w = (const float*)d_in[9];
  EdgePtrs ep;
  for (int b = 0; b < 4; b++) {
    ep.rows[b] = (const int*)d_in[10 + 3 * b];
    ep.cols[b] = (const int*)d_in[11 + 3 * b];
    ep.vals[b] = (const float*)d_in[12 + 3 * b];
  }

  float* out = (float*)d_out;
  float* user_out = out;
  float* item_out = out + (size_t)NU * DD;
  float* l2nU = item_out + (size_t)NI * DD;
  float* l2nI = l2nU + (size_t)4 * NU * DD;
  float* u_slot[3];
  float* i_slot[3];
  {
    float* p = l2nI + (size_t)4 * NI * DD;
    for (int b = 0; b < 3; b++) {
      u_slot[b] = p; p += (size_t)NU * DD;
      i_slot[b] = p; p += (size_t)NI * DD;
    }
  }

  const size_t binsl = (size_t)2 * NNZ_E * 8;          // 32 MB per behavior slot
  const size_t item_bf_sz = (size_t)4 * NI * DD * 2;   // ~41 MB
  const size_t user_bf_sz = (size_t)4 * NU * DD * 2;   // ~82 MB
  const size_t mean_sz = (size_t)(NU + NI) * DD * 4;   // ~61 MB
  const size_t smalls = 8u << 20;

  int batchB; bool bfI, bfU;
  if (ws_size >= 4 * binsl + item_bf_sz + user_bf_sz + mean_sz + smalls) { batchB = 4; bfI = bfU = true; }
  else if (ws_size >= 2 * binsl + item_bf_sz + user_bf_sz + smalls) { batchB = 2; bfI = bfU = true; }
  else if (ws_size >= binsl + item_bf_sz + user_bf_sz + smalls) { batchB = 1; bfI = bfU = true; }
  else if (ws_size >= binsl + item_bf_sz + smalls) { batchB = 1; bfI = true; bfU = false; }
  else { batchB = 1; bfI = bfU = false; }

  char* w = (char*)d_ws;
  auto alloc = [&](size_t bytes) {
    char* r = w;
    w += (bytes + 255) & ~(size_t)255;
    return r;
  };
  int2* binned = (int2*)alloc((size_t)batchB * binsl);
  unsigned short* itemB = bfI ? (unsigned short*)alloc(item_bf_sz) : nullptr;
  unsigned short* userB = bfU ? (unsigned short*)alloc(user_bf_sz) : nullptr;
  float* meanU = nullptr;
  float* meanI = nullptr;
  if (batchB == 4) {
    meanU = (float*)alloc((size_t)NU * DD * 4);
    meanI = (float*)alloc((size_t)NI * DD * 4);
  }
  int* cntA = (int*)alloc(4 * 2 * NBPAD * 4);
  int* baseA = (int*)alloc(4 * 2 * BSTRIDE * 4);
  int* gcurA = (int*)alloc(4 * 2 * NBPAD * 4);
  int* rpU = (int*)alloc((size_t)4 * (NU + 1) * 4);
  int* rpI = (int*)alloc((size_t)4 * (NI + 1) * 4);
  float* colsums = (float*)alloc(NREP * 1024 * 4);
  float* invs = (float*)alloc(8 * DD * 4);

  hipMemsetAsync(cntA, 0, 4 * 2 * NBPAD * 4, stream);
  histB_k<<<dim3(256, 4), 256, 0, stream>>>(ep, cntA);
  scanb_k<<<8, 512, 0, stream>>>(cntA, baseA, gcurA);

  const int nchunks = (NNZ_E + BIN_E - 1) / BIN_E;  // 245

  if (batchB == 4) {
    bin_k<<<dim3(nchunks, 2, 4), 512, 0, stream>>>(ep, 0, gcurA, binned);
    sort3_k<<<4 * (NBU + NBI), 512, 0, stream>>>(rpU, rpI, 0, baseA, binned);

    ConvPtrs cp;
    for (int b = 0; b < 4; b++) {
      cp.src[b] = ii[b]; cp.dst[b] = itemB + (size_t)b * NI * DD; cp.n4[b] = NI * DD / 4;
      cp.src[4 + b] = uu[b]; cp.dst[4 + b] = userB + (size_t)b * NU * DD; cp.n4[4 + b] = NU * DD / 4;
    }
    convA_k<<<dim3(512, 8), 256, 0, stream>>>(cp);
    hipMemsetAsync(colsums, 0, NREP * 1024 * 4, stream);

    GAll g;
    for (int b = 0; b < 4; b++) {
      g.rp[0][b] = rpU + (size_t)b * (NU + 1);
      g.pairs[0][b] = binned + ((size_t)b * 2 + 0) * NNZ_E;
      g.xt[0][b] = itemB + (size_t)b * NI * DD;
      g.out[0][b] = l2nU + (size_t)b * NU * DD;
      g.rp[1][b] = rpI + (size_t)b * (NI + 1);
      g.pairs[1][b] = binned + ((size_t)b * 2 + 1) * NNZ_E;
      g.xt[1][b] = userB + (size_t)b * NU * DD;
      g.out[1][b] = l2nI + (size_t)b * NI * DD;
    }
    g.meanb[0] = meanU; g.meanb[1] = meanI;
    g.colsums = colsums;
    gatherD_k<<<NU / 32, 256, 0, stream>>>(g, 0);   // 2500 blocks
    gatherD_k<<<NI / 32, 256, 0, stream>>>(g, 1);   // 1250 blocks

    gemm2_k<<<NU / 64 + NI / 64, 256, 0, stream>>>(meanU, meanI, u_w, i_w, user_out, item_out);

    DupPtrs dp;
    for (int b = 0; b < 4; b++) {
      dp.d[b] = (b < 3) ? u_slot[b] : nullptr;
      dp.d[4 + b] = (b < 3) ? i_slot[b] : nullptr;
    }
    scaleall2_k<<<dim3(1024, 8), 256, 0, stream>>>(l2nU, l2nI, colsums, dp);
  } else {
    if (bfI)
      for (int b = 0; b < 4; b++)
        conv_k<<<512, 256, 0, stream>>>(ii[b], itemB + (size_t)b * NI * DD, NI * DD / 4);
    if (bfU)
      for (int b = 0; b < 4; b++)
        conv_k<<<512, 256, 0, stream>>>(uu[b], userB + (size_t)b * NU * DD, NU * DD / 4);
    for (int b0 = 0; b0 < 4; b0 += batchB) {
      bin_k<<<dim3(nchunks, 2, batchB), 512, 0, stream>>>(ep, b0, gcurA, binned);
      sort3_k<<<batchB * (NBU + NBI), 512, 0, stream>>>(rpU, rpI, b0, baseA, binned);
      for (int j = 0; j < batchB; j++) {
        int b = b0 + j;
        const void* xt0 = bfI ? (const void*)(itemB + (size_t)b * NI * DD) : (const void*)ii[b];
        const void* xt1 = bfU ? (const void*)(userB + (size_t)b * NU * DD) : (const void*)uu[b];
        gather_k<<<10000, 256, 0, stream>>>(rpU + (size_t)b * (NU + 1),
                                            binned + ((size_t)j * 2 + 0) * NNZ_E, xt0, bfI ? 1 : 0,
                                            l2nU + (size_t)b * NU * DD, (b < 3) ? u_slot[b] : nullptr, NU);
        gather_k<<<5000, 256, 0, stream>>>(rpI + (size_t)b * (NI + 1),
                                           binned + ((size_t)j * 2 + 1) * NNZ_E, xt1, bfU ? 1 : 0,
                                           l2nI + (size_t)b * NI * DD, (b < 3) ? i_slot[b] : nullptr, NI);
      }
    }
    gemm_sig_k<<<NU / 64, 256, 0, stream>>>(l2nU, (size_t)NU * DD, u_w, user_out, NU);
    gemm_sig_k<<<NI / 64, 256, 0, stream>>>(l2nI, (size_t)NI * DD, i_w, item_out, NI);
    hipMemsetAsync(colsums, 0, NREP * 1024 * 4, stream);
    colsq_k<<<dim3(512, 4), 256, 0, stream>>>(l2nU, (size_t)NU * DD, NU, colsums);
    colsq_k<<<dim3(512, 4), 256, 0, stream>>>(l2nI, (size_t)NI * DD, NI, colsums + 4 * DD);
    inv_k<<<4, 256, 0, stream>>>(colsums, invs, 8 * DD, 1);
    scaleall_k<<<dim3(1024, 8), 256, 0, stream>>>(l2nU, l2nI, invs);
  }
}

// Round 8
// 1293.438 us; speedup vs baseline: 1.1821x; 1.1821x over previous
//
#include <hip/hip_runtime.h>

#define NU 80000
#define NI 40000
#define DD 128
#define NNZ_E 2000000
#define EPSN 1e-12f
#define BWROWS 256
#define NBU 313   // ceil(NU/256)
#define NBI 157   // ceil(NI/256)
#define NBPAD 320
#define BSTRIDE 336
#define BIN_E 8192
#define S2CAP 16384
#define NREP 4    // colsum atomic shards

struct EdgePtrs { const int* rows[4]; const int* cols[4]; const float* vals[4]; };

struct GAll {
  const int* rp[2][4];
  const int2* pairs[2][4];
  const unsigned short* xt[2][4];
  float* out[2][4];
  float* meanb[2];
  float* colsums;
};

struct DupPtrs { float* d[8]; };   // raw u0..u2 (y=0..2), i0..i2 (y=4..6); null else

struct ConvPtrs { const float* src[8]; unsigned short* dst[8]; int n4[8]; };

typedef float f32x4 __attribute__((ext_vector_type(4)));
__device__ inline void nts(float4 v, float4* p) {
  f32x4 w = {v.x, v.y, v.z, v.w};
  __builtin_nontemporal_store(w, (f32x4*)p);
}

__device__ inline unsigned short f2bf(float f) {
  unsigned int u = __float_as_uint(f);
  u += 0x7FFFu + ((u >> 16) & 1u);   // RNE
  return (unsigned short)(u >> 16);
}
__device__ inline float bf2f(unsigned short h) {
  return __uint_as_float((unsigned)h << 16);
}

// -------- fused bf16 conversion of all 8 tables --------
__global__ __launch_bounds__(256) void convA_k(ConvPtrs cp) {
  int y = blockIdx.y;
  const float4* __restrict__ src = (const float4*)cp.src[y];
  ushort4* __restrict__ dst = (ushort4*)cp.dst[y];
  int n4 = cp.n4[y];
  int stride = blockDim.x * gridDim.x;
  for (int i = blockIdx.x * blockDim.x + threadIdx.x; i < n4; i += stride) {
    float4 f = src[i];
    ushort4 h;
    h.x = f2bf(f.x); h.y = f2bf(f.y); h.z = f2bf(f.z); h.w = f2bf(f.w);
    dst[i] = h;
  }
}

__global__ __launch_bounds__(256) void conv_k(const float* __restrict__ src,
                                              unsigned short* __restrict__ dst, int n4) {
  int stride = blockDim.x * gridDim.x;
  for (int i = blockIdx.x * blockDim.x + threadIdx.x; i < n4; i += stride) {
    float4 f = ((const float4*)src)[i];
    ushort4 h;
    h.x = f2bf(f.x); h.y = f2bf(f.y); h.z = f2bf(f.z); h.w = f2bf(f.w);
    ((ushort4*)dst)[i] = h;
  }
}

// -------- bucket-level histogram (LDS-privatized), all behaviors --------
__global__ __launch_bounds__(256) void histB_k(EdgePtrs ep, int* cntA) {
  int b = blockIdx.y;
  const int* __restrict__ rows = ep.rows[b];
  const int* __restrict__ cols = ep.cols[b];
  __shared__ int lh[NBU + NBI];
  for (int i = threadIdx.x; i < NBU + NBI; i += blockDim.x) lh[i] = 0;
  __syncthreads();
  int stride = blockDim.x * gridDim.x;
  for (int e = blockIdx.x * blockDim.x + threadIdx.x; e < NNZ_E; e += stride) {
    atomicAdd(&lh[rows[e] >> 8], 1);
    atomicAdd(&lh[NBU + (cols[e] >> 8)], 1);
  }
  __syncthreads();
  int* cu = cntA + (b * 2 + 0) * NBPAD;
  int* ci = cntA + (b * 2 + 1) * NBPAD;
  for (int i = threadIdx.x; i < NBU + NBI; i += blockDim.x) {
    int v = lh[i];
    if (v) {
      if (i < NBU) atomicAdd(&cu[i], v);
      else atomicAdd(&ci[i - NBU], v);
    }
  }
}

// -------- bucket scan: 8 arrays of <=313 values --------
__global__ __launch_bounds__(512) void scanb_k(const int* cntA, int* baseA, int* gcurA) {
  __shared__ int wsums[9];
  int a = blockIdx.x;              // b*2 + dir
  int dir = a & 1;
  int n = dir ? NBI : NBU;
  const int* cnt = cntA + a * NBPAD;
  int* base = baseA + a * BSTRIDE;
  int* gcur = gcurA + a * NBPAD;
  int t = threadIdx.x, lane = t & 63, w = t >> 6;
  int v = (t < n) ? cnt[t] : 0;
  int s = v;
  #pragma unroll
  for (int off = 1; off < 64; off <<= 1) {
    int x = __shfl_up(s, off);
    if (lane >= off) s += x;
  }
  if (lane == 63) wsums[w] = s;
  __syncthreads();
  if (t == 0) {
    int run = 0;
    for (int k = 0; k < 8; k++) { int x = wsums[k]; wsums[k] = run; run += x; }
    wsums[8] = run;
  }
  __syncthreads();
  int ex = wsums[w] + s - v;
  if (t < n) { base[t] = ex; gcur[t] = ex; }
  if (t == 0) base[n] = wsums[8];
}

// -------- pass 1: counting-sort chunks by bucket, coalesced flush --------
__global__ __launch_bounds__(512) void bin_k(EdgePtrs ep, int b0, int* gcurA, int2* binned) {
  __shared__ int2 stage[BIN_E];     // 64 KB
  __shared__ int lh[NBPAD], lscan[NBPAD], lcur[NBPAD], gpos[NBPAD];
  __shared__ int wsums[9];
  int dir = blockIdx.y, j = blockIdx.z, b = b0 + j;
  int NB = dir ? NBI : NBU;
  const int* __restrict__ dst = dir ? ep.cols[b] : ep.rows[b];
  const int* __restrict__ src = dir ? ep.rows[b] : ep.cols[b];
  const float* __restrict__ vals = ep.vals[b];
  int* gcur = gcurA + (b * 2 + dir) * NBPAD;
  int2* out = binned + ((size_t)j * 2 + dir) * NNZ_E;
  int t = threadIdx.x;
  int e0 = blockIdx.x * BIN_E;
  int nh = min(BIN_E, NNZ_E - e0);
  for (int i = t; i < NBPAD; i += 512) lh[i] = 0;
  __syncthreads();
  for (int i = t; i < nh; i += 512) atomicAdd(&lh[dst[e0 + i] >> 8], 1);
  __syncthreads();
  {
    int lane = t & 63, w = t >> 6;
    int v = (t < NB) ? lh[t] : 0;
    int s = v;
    #pragma unroll
    for (int off = 1; off < 64; off <<= 1) {
      int x = __shfl_up(s, off);
      if (lane >= off) s += x;
    }
    if (lane == 63) wsums[w] = s;
    __syncthreads();
    if (t == 0) {
      int run = 0;
      for (int k = 0; k < 8; k++) { int x = wsums[k]; wsums[k] = run; run += x; }
      wsums[8] = run;
    }
    __syncthreads();
    int ex = wsums[w] + s - v;
    if (t < NB) { lscan[t] = ex; lcur[t] = ex; gpos[t] = atomicAdd(&gcur[t], v); }
  }
  __syncthreads();
  for (int i = t; i < nh; i += 512) {
    int d = dst[e0 + i], s = src[e0 + i];
    int k = d >> 8;
    int pos = atomicAdd(&lcur[k], 1);
    stage[pos] = make_int2(s | ((d & 255) << 17), __float_as_int(vals[e0 + i]));
  }
  __syncthreads();
  int w = t >> 6, lane = t & 63;
  for (int k = w; k < NB; k += 8) {
    int c = lh[k];
    const int2* sp = stage + lscan[k];
    int2* gp = out + gpos[k];
    for (int i = lane; i < c; i += 64) gp[i] = sp[i];
  }
}

// -------- pass 2: per-bucket exact-row sort + CSR row_ptr emission --------
__global__ __launch_bounds__(512) void sort3_k(int* rpU, int* rpI, int b0,
                                               const int* baseA, int2* binned) {
  __shared__ int2 stage[S2CAP];   // 128 KB
  __shared__ int lh[256];
  __shared__ int excl[257];
  __shared__ int lcur[256];
  __shared__ int wsums[5];
  int gb = blockIdx.x;
  int j = gb / (NBU + NBI);
  int r = gb - j * (NBU + NBI);
  int dir = (r >= NBU) ? 1 : 0;
  int k = dir ? (r - NBU) : r;
  int b = b0 + j;
  int n = dir ? NI : NU;
  int* rp = dir ? (rpI + (size_t)b * (NI + 1)) : (rpU + (size_t)b * (NU + 1));
  const int* base = baseA + (b * 2 + dir) * BSTRIDE;
  int2* bb = binned + ((size_t)j * 2 + dir) * NNZ_E;
  int row0 = k << 8;
  int nrows = min(BWROWS, n - row0);
  int base0 = base[k];
  int tot = base[k + 1] - base0;
  int t = threadIdx.x;
  if (t < 256) lh[t] = 0;
  __syncthreads();
  for (int i = t; i < tot; i += 512) atomicAdd(&lh[(bb[base0 + i].x >> 17) & 255], 1);
  __syncthreads();
  int v = 0, s = 0;
  if (t < 256) {
    int lane = t & 63, w = t >> 6;
    v = lh[t]; s = v;
    #pragma unroll
    for (int off = 1; off < 64; off <<= 1) {
      int x = __shfl_up(s, off);
      if (lane >= off) s += x;
    }
    if (lane == 63) wsums[w] = s;
  }
  __syncthreads();
  if (t == 0) {
    int run = 0;
    for (int q = 0; q < 4; q++) { int x = wsums[q]; wsums[q] = run; run += x; }
    wsums[4] = run;
  }
  __syncthreads();
  if (t < 256) {
    int ex = wsums[t >> 6] + s - v;
    excl[t] = ex; lcur[t] = ex;
  }
  if (t == 0) excl[256] = wsums[4];
  __syncthreads();
  if (t <= nrows) rp[row0 + t] = base0 + excl[t];
  for (int i = t; i < tot; i += 512) {
    int2 p = bb[base0 + i];
    int ld = (p.x >> 17) & 255;
    int pos = atomicAdd(&lcur[ld], 1);
    stage[pos] = make_int2(p.x & 0x1FFFF, p.y);
  }
  __syncthreads();
  for (int i = t; i < tot; i += 512) bb[base0 + i] = stage[i];
}

// -------- fused gather (round-5 winner): b-inner, grid-stride rows, 4-edge unroll --------
__global__ __launch_bounds__(256) void gather4_k(GAll gm, int dir, int nrows, int ngroups) {
  int gid = blockIdx.x * 8 + (threadIdx.x >> 5);
  int lane = threadIdx.x & 31;
  int t = threadIdx.x;
  float4 z = make_float4(0.f, 0.f, 0.f, 0.f);
  float4 sq0 = z, sq1 = z, sq2 = z, sq3 = z;
  for (int r = gid; r < nrows; r += ngroups) {
    float4 mean = z;
    #pragma unroll
    for (int b = 0; b < 4; b++) {
      const int* rp = gm.rp[dir][b];
      const int2* __restrict__ pairs = gm.pairs[dir][b];
      const ushort4* __restrict__ x4 = (const ushort4*)gm.xt[dir][b];
      int beg = rp[r], end = rp[r + 1];
      float4 a0 = z, a1 = z;
      int e = beg;
      for (; e + 3 < end; e += 4) {
        int2 p0 = pairs[e], p1 = pairs[e + 1], p2 = pairs[e + 2], p3 = pairs[e + 3];
        ushort4 h0 = x4[(size_t)p0.x * 32 + lane];
        ushort4 h1 = x4[(size_t)p1.x * 32 + lane];
        ushort4 h2 = x4[(size_t)p2.x * 32 + lane];
        ushort4 h3 = x4[(size_t)p3.x * 32 + lane];
        float v0 = __int_as_float(p0.y), v1 = __int_as_float(p1.y);
        float v2 = __int_as_float(p2.y), v3 = __int_as_float(p3.y);
        a0.x += v0 * bf2f(h0.x); a0.y += v0 * bf2f(h0.y);
        a0.z += v0 * bf2f(h0.z); a0.w += v0 * bf2f(h0.w);
        a1.x += v1 * bf2f(h1.x); a1.y += v1 * bf2f(h1.y);
        a1.z += v1 * bf2f(h1.z); a1.w += v1 * bf2f(h1.w);
        a0.x += v2 * bf2f(h2.x); a0.y += v2 * bf2f(h2.y);
        a0.z += v2 * bf2f(h2.z); a0.w += v2 * bf2f(h2.w);
        a1.x += v3 * bf2f(h3.x); a1.y += v3 * bf2f(h3.y);
        a1.z += v3 * bf2f(h3.z); a1.w += v3 * bf2f(h3.w);
      }
      for (; e < end; e++) {
        int2 p = pairs[e];
        ushort4 h = x4[(size_t)p.x * 32 + lane];
        float v = __int_as_float(p.y);
        a0.x += v * bf2f(h.x); a0.y += v * bf2f(h.y);
        a0.z += v * bf2f(h.z); a0.w += v * bf2f(h.w);
      }
      float4 res = make_float4(a0.x + a1.x, a0.y + a1.y, a0.z + a1.z, a0.w + a1.w);
      nts(res, (float4*)gm.out[dir][b] + (size_t)r * 32 + lane);
      mean.x += res.x; mean.y += res.y; mean.z += res.z; mean.w += res.w;
      float4* sqp = (b == 0) ? &sq0 : (b == 1) ? &sq1 : (b == 2) ? &sq2 : &sq3;
      sqp->x += res.x * res.x; sqp->y += res.y * res.y;
      sqp->z += res.z * res.z; sqp->w += res.w * res.w;
    }
    mean.x *= 0.25f; mean.y *= 0.25f; mean.z *= 0.25f; mean.w *= 0.25f;
    ((float4*)gm.meanb[dir])[(size_t)r * 32 + lane] = mean;
  }
  // block-level colsq reduction
  __shared__ float csq[512];
  csq[t] = 0.f; csq[t + 256] = 0.f;
  __syncthreads();
  int cb = lane * 4;
  atomicAdd(&csq[0 * 128 + cb + 0], sq0.x); atomicAdd(&csq[0 * 128 + cb + 1], sq0.y);
  atomicAdd(&csq[0 * 128 + cb + 2], sq0.z); atomicAdd(&csq[0 * 128 + cb + 3], sq0.w);
  atomicAdd(&csq[1 * 128 + cb + 0], sq1.x); atomicAdd(&csq[1 * 128 + cb + 1], sq1.y);
  atomicAdd(&csq[1 * 128 + cb + 2], sq1.z); atomicAdd(&csq[1 * 128 + cb + 3], sq1.w);
  atomicAdd(&csq[2 * 128 + cb + 0], sq2.x); atomicAdd(&csq[2 * 128 + cb + 1], sq2.y);
  atomicAdd(&csq[2 * 128 + cb + 2], sq2.z); atomicAdd(&csq[2 * 128 + cb + 3], sq2.w);
  atomicAdd(&csq[3 * 128 + cb + 0], sq3.x); atomicAdd(&csq[3 * 128 + cb + 1], sq3.y);
  atomicAdd(&csq[3 * 128 + cb + 2], sq3.z); atomicAdd(&csq[3 * 128 + cb + 3], sq3.w);
  __syncthreads();
  float* dst = gm.colsums + (blockIdx.x & (NREP - 1)) * 1024 + dir * 512;
  atomicAdd(&dst[t], csq[t]);
  atomicAdd(&dst[t + 256], csq[t + 256]);
}

// -------- fallback per-behavior gather (small-ws path) --------
__global__ __launch_bounds__(256) void gather_k(const int* __restrict__ rp, const int2* __restrict__ pairs,
                                                const void* __restrict__ xt, int isbf,
                                                float* __restrict__ out1, float* __restrict__ out2,
                                                int nrows) {
  int gid = blockIdx.x * 8 + (threadIdx.x >> 5);
  int lane = threadIdx.x & 31;
  int tot = gridDim.x * 8;
  for (int r = gid; r < nrows; r += tot) {
    int beg = rp[r], end = rp[r + 1];
    float4 a0 = make_float4(0.f, 0.f, 0.f, 0.f);
    int e = beg;
    if (isbf) {
      const ushort4* __restrict__ x4 = (const ushort4*)xt;
      for (; e < end; e++) {
        int2 p = pairs[e];
        ushort4 h = x4[(size_t)p.x * 32 + lane];
        float v = __int_as_float(p.y);
        a0.x += v * bf2f(h.x); a0.y += v * bf2f(h.y);
        a0.z += v * bf2f(h.z); a0.w += v * bf2f(h.w);
      }
    } else {
      const float4* __restrict__ x4 = (const float4*)xt;
      for (; e < end; e++) {
        int2 p = pairs[e];
        float4 xv = x4[(size_t)p.x * 32 + lane];
        float v = __int_as_float(p.y);
        a0.x += v * xv.x; a0.y += v * xv.y; a0.z += v * xv.z; a0.w += v * xv.w;
      }
    }
    ((float4*)out1)[(size_t)r * 32 + lane] = a0;
    if (out2) ((float4*)out2)[(size_t)r * 32 + lane] = a0;
  }
}

// ---------------- combined GEMM (mean buffers) + sigmoid ----------------
__global__ __launch_bounds__(256) void gemm2_k(const float* __restrict__ meanU,
                                               const float* __restrict__ meanI,
                                               const float* __restrict__ u_w,
                                               const float* __restrict__ i_w,
                                               float* __restrict__ user_out,
                                               float* __restrict__ item_out) {
  __shared__ float wl[DD * DD];
  __shared__ float rl[8][DD];
  int blk = blockIdx.x;
  const float* mean; const float* W; float* outp; int n; int row0;
  if (blk < NU / 64) { mean = meanU; W = u_w; outp = user_out; n = NU; row0 = blk * 64; }
  else { mean = meanI; W = i_w; outp = item_out; n = NI; row0 = (blk - NU / 64) * 64; }
  for (int i = threadIdx.x; i < DD * DD / 4; i += blockDim.x)
    ((float4*)wl)[i] = ((const float4*)W)[i];
  int c = threadIdx.x & 127;
  int g = threadIdx.x >> 7;
  for (int rr = 0; rr < 64; rr += 8) {
    int rbase = row0 + rr;
    __syncthreads();
    for (int i = threadIdx.x; i < 8 * DD; i += blockDim.x) {
      int lr = i >> 7, lc = i & 127;
      int r = rbase + lr;
      rl[lr][lc] = (r < n) ? mean[(size_t)r * DD + lc] : 0.f;
    }
    __syncthreads();
    float acc0 = 0.f, acc1 = 0.f, acc2 = 0.f, acc3 = 0.f;
    #pragma unroll 4
    for (int k = 0; k < DD; k++) {
      float wv = wl[k * DD + c];
      acc0 += rl[g * 4 + 0][k] * wv;
      acc1 += rl[g * 4 + 1][k] * wv;
      acc2 += rl[g * 4 + 2][k] * wv;
      acc3 += rl[g * 4 + 3][k] * wv;
    }
    float accs[4] = {acc0, acc1, acc2, acc3};
    for (int jj = 0; jj < 4; jj++) {
      int r = rbase + g * 4 + jj;
      if (r < n) outp[(size_t)r * DD + c] = 1.f / (1.f + __expf(-accs[jj]));
    }
  }
}

// fallback gemm (reads 4 slices)
__global__ __launch_bounds__(256) void gemm_sig_k(const float* __restrict__ x, size_t sstride,
                                                  const float* __restrict__ W, float* __restrict__ out,
                                                  int n) {
  __shared__ float wl[DD * DD];
  __shared__ float rl[8][DD];
  for (int i = threadIdx.x; i < DD * DD / 4; i += blockDim.x)
    ((float4*)wl)[i] = ((const float4*)W)[i];
  int c = threadIdx.x & 127;
  int g = threadIdx.x >> 7;
  int row0 = blockIdx.x * 64;
  for (int rr = 0; rr < 64; rr += 8) {
    int rbase = row0 + rr;
    __syncthreads();
    for (int i = threadIdx.x; i < 8 * DD; i += blockDim.x) {
      int lr = i >> 7, lc = i & 127;
      int r = rbase + lr;
      float m = 0.f;
      if (r < n) {
        size_t off = (size_t)r * DD + lc;
        m = 0.25f * (x[off] + x[off + sstride] + x[off + 2 * sstride] + x[off + 3 * sstride]);
      }
      rl[lr][lc] = m;
    }
    __syncthreads();
    float acc0 = 0.f, acc1 = 0.f, acc2 = 0.f, acc3 = 0.f;
    #pragma unroll 4
    for (int k = 0; k < DD; k++) {
      float wv = wl[k * DD + c];
      acc0 += rl[g * 4 + 0][k] * wv;
      acc1 += rl[g * 4 + 1][k] * wv;
      acc2 += rl[g * 4 + 2][k] * wv;
      acc3 += rl[g * 4 + 3][k] * wv;
    }
    float accs[4] = {acc0, acc1, acc2, acc3};
    for (int jj = 0; jj < 4; jj++) {
      int r = rbase + g * 4 + jj;
      if (r < n) out[(size_t)r * DD + c] = 1.f / (1.f + __expf(-accs[jj]));
    }
  }
}

// ---------------- colsq (fallback) / inv / scale ----------------
__global__ __launch_bounds__(256) void colsq_k(const float* __restrict__ base, size_t sstride, int n,
                                               float* __restrict__ sums) {
  int b = blockIdx.y;
  const float* x = base + (size_t)b * sstride;
  int c = threadIdx.x & 127;
  int rh = threadIdx.x >> 7;
  float acc = 0.f;
  for (int r = blockIdx.x * 2 + rh; r < n; r += gridDim.x * 2) {
    float v = x[(size_t)r * DD + c];
    acc += v * v;
  }
  __shared__ float red[256];
  red[threadIdx.x] = acc;
  __syncthreads();
  if (threadIdx.x < 128) atomicAdd(&sums[b * DD + threadIdx.x], red[threadIdx.x] + red[threadIdx.x + 128]);
}

__global__ void inv_k(const float* __restrict__ sums, float* __restrict__ inv, int n, int nrep) {
  int i = blockIdx.x * blockDim.x + threadIdx.x;
  if (i < n) {
    float s = 0.f;
    for (int r = 0; r < nrep; r++) s += sums[r * 1024 + i];
    inv[i] = 1.f / fmaxf(sqrtf(s), EPSN);
  }
}

// main path: inv from sharded colsums; writes raw dup + scaled slice (both nt)
__global__ __launch_bounds__(256) void scaleall2_k(float* __restrict__ l2nU, float* __restrict__ l2nI,
                                                   const float* __restrict__ colsums, DupPtrs dp) {
  __shared__ float sinv[DD];
  int y = blockIdx.y;  // 0..3 = U slices, 4..7 = I slices
  int t = threadIdx.x;
  if (t < DD) {
    float s = 0.f;
    #pragma unroll
    for (int rr = 0; rr < NREP; rr++) s += colsums[rr * 1024 + y * DD + t];
    sinv[t] = 1.f / fmaxf(sqrtf(s), EPSN);
  }
  __syncthreads();
  float4* b4;
  size_t slice;
  if (y < 4) { b4 = (float4*)l2nU + (size_t)y * NU * 32; slice = (size_t)NU * 32; }
  else { b4 = (float4*)l2nI + (size_t)(y - 4) * NI * 32; slice = (size_t)NI * 32; }
  float4* dupp = (float4*)dp.d[y];
  const float4* inv4 = (const float4*)sinv;
  size_t stride = (size_t)blockDim.x * gridDim.x;
  for (size_t i = (size_t)blockIdx.x * blockDim.x + threadIdx.x; i < slice; i += stride) {
    float4 s = inv4[i & 31];
    float4 v = b4[i];
    if (dupp) nts(v, dupp + i);
    v.x *= s.x; v.y *= s.y; v.z *= s.z; v.w *= s.w;
    nts(v, b4 + i);
  }
}

// fallback scale (external invs)
__global__ __launch_bounds__(256) void scaleall_k(float* __restrict__ l2nU, float* __restrict__ l2nI,
                                                  const float* __restrict__ invs) {
  int y = blockIdx.y;
  float4* b4;
  size_t slice;
  if (y < 4) { b4 = (float4*)l2nU + (size_t)y * NU * 32; slice = (size_t)NU * 32; }
  else { b4 = (float4*)l2nI + (size_t)(y - 4) * NI * 32; slice = (size_t)NI * 32; }
  const float4* inv4 = (const float4*)invs + (size_t)y * 32;
  size_t stride = (size_t)blockDim.x * gridDim.x;
  for (size_t i = (size_t)blockIdx.x * blockDim.x + threadIdx.x; i < slice; i += stride) {
    float4 s = inv4[i & 31];
    float4 v = b4[i];
    v.x *= s.x; v.y *= s.y; v.z *= s.z; v.w *= s.w;
    b4[i] = v;
  }
}

// ---------------- host ----------------
extern "C" void kernel_launch(void* const* d_in, const int* in_sizes, int n_in,
                              void* d_out, int out_size, void* d_ws, size_t ws_size,
                              hipStream_t stream) {
  const float* user_emb = (const float*)d_in[0];
  const float* item_emb = (const float*)d_in[1];
  const float* uu[4] = {(const float*)d_in[2], (const float*)d_in[4], (const float*)d_in[6], user_emb};
  const float* ii[4] = {(const float*)d_in[3], (const float*)d_in[5], (const float*)d_in[7], item_emb};
  const float* u_w = (const float*)d_in[8];
  const float* i_w = (const float*)d_in[9];
  EdgePtrs ep;
  for (int b = 0; b < 4; b++) {
    ep.rows[b] = (const int*)d_in[10 + 3 * b];
    ep.cols[b] = (const int*)d_in[11 + 3 * b];
    ep.vals[b] = (const float*)d_in[12 + 3 * b];
  }

  float* out = (float*)d_out;
  float* user_out = out;
  float* item_out = out + (size_t)NU * DD;
  float* l2nU = item_out + (size_t)NI * DD;
  float* l2nI = l2nU + (size_t)4 * NU * DD;
  float* u_slot[3];
  float* i_slot[3];
  {
    float* p = l2nI + (size_t)4 * NI * DD;
    for (int b = 0; b < 3; b++) {
      u_slot[b] = p; p += (size_t)NU * DD;
      i_slot[b] = p; p += (size_t)NI * DD;
    }
  }

  const size_t binsl = (size_t)2 * NNZ_E * 8;          // 32 MB per behavior slot
  const size_t item_bf_sz = (size_t)4 * NI * DD * 2;   // ~41 MB
  const size_t user_bf_sz = (size_t)4 * NU * DD * 2;   // ~82 MB
  const size_t mean_sz = (size_t)(NU + NI) * DD * 4;   // ~61 MB
  const size_t smalls = 8u << 20;

  int batchB; bool bfI, bfU;
  if (ws_size >= 4 * binsl + item_bf_sz + user_bf_sz + mean_sz + smalls) { batchB = 4; bfI = bfU = true; }
  else if (ws_size >= 2 * binsl + item_bf_sz + user_bf_sz + smalls) { batchB = 2; bfI = bfU = true; }
  else if (ws_size >= binsl + item_bf_sz + user_bf_sz + smalls) { batchB = 1; bfI = bfU = true; }
  else if (ws_size >= binsl + item_bf_sz + smalls) { batchB = 1; bfI = true; bfU = false; }
  else { batchB = 1; bfI = bfU = false; }

  char* w = (char*)d_ws;
  auto alloc = [&](size_t bytes) {
    char* r = w;
    w += (bytes + 255) & ~(size_t)255;
    return r;
  };
  int2* binned = (int2*)alloc((size_t)batchB * binsl);
  unsigned short* itemB = bfI ? (unsigned short*)alloc(item_bf_sz) : nullptr;
  unsigned short* userB = bfU ? (unsigned short*)alloc(user_bf_sz) : nullptr;
  float* meanU = nullptr;
  float* meanI = nullptr;
  if (batchB == 4) {
    meanU = (float*)alloc((size_t)NU * DD * 4);
    meanI = (float*)alloc((size_t)NI * DD * 4);
  }
  int* cntA = (int*)alloc(4 * 2 * NBPAD * 4);
  int* baseA = (int*)alloc(4 * 2 * BSTRIDE * 4);
  int* gcurA = (int*)alloc(4 * 2 * NBPAD * 4);
  int* rpU = (int*)alloc((size_t)4 * (NU + 1) * 4);
  int* rpI = (int*)alloc((size_t)4 * (NI + 1) * 4);
  float* colsums = (float*)alloc(NREP * 1024 * 4);
  float* invs = (float*)alloc(8 * DD * 4);

  hipMemsetAsync(cntA, 0, 4 * 2 * NBPAD * 4, stream);
  histB_k<<<dim3(256, 4), 256, 0, stream>>>(ep, cntA);
  scanb_k<<<8, 512, 0, stream>>>(cntA, baseA, gcurA);

  const int nchunks = (NNZ_E + BIN_E - 1) / BIN_E;  // 245

  if (batchB == 4) {
    bin_k<<<dim3(nchunks, 2, 4), 512, 0, stream>>>(ep, 0, gcurA, binned);
    sort3_k<<<4 * (NBU + NBI), 512, 0, stream>>>(rpU, rpI, 0, baseA, binned);

    ConvPtrs cp;
    for (int b = 0; b < 4; b++) {
      cp.src[b] = ii[b]; cp.dst[b] = itemB + (size_t)b * NI * DD; cp.n4[b] = NI * DD / 4;
      cp.src[4 + b] = uu[b]; cp.dst[4 + b] = userB + (size_t)b * NU * DD; cp.n4[4 + b] = NU * DD / 4;
    }
    convA_k<<<dim3(512, 8), 256, 0, stream>>>(cp);
    hipMemsetAsync(colsums, 0, NREP * 1024 * 4, stream);

    GAll g;
    for (int b = 0; b < 4; b++) {
      g.rp[0][b] = rpU + (size_t)b * (NU + 1);
      g.pairs[0][b] = binned + ((size_t)b * 2 + 0) * NNZ_E;
      g.xt[0][b] = itemB + (size_t)b * NI * DD;
      g.out[0][b] = l2nU + (size_t)b * NU * DD;
      g.rp[1][b] = rpI + (size_t)b * (NI + 1);
      g.pairs[1][b] = binned + ((size_t)b * 2 + 1) * NNZ_E;
      g.xt[1][b] = userB + (size_t)b * NU * DD;
      g.out[1][b] = l2nI + (size_t)b * NI * DD;
    }
    g.meanb[0] = meanU; g.meanb[1] = meanI;
    g.colsums = colsums;
    gather4_k<<<2500, 256, 0, stream>>>(g, 0, NU, 2500 * 8);
    gather4_k<<<1250, 256, 0, stream>>>(g, 1, NI, 1250 * 8);

    gemm2_k<<<NU / 64 + NI / 64, 256, 0, stream>>>(meanU, meanI, u_w, i_w, user_out, item_out);

    DupPtrs dp;
    for (int b = 0; b < 4; b++) {
      dp.d[b] = (b < 3) ? u_slot[b] : nullptr;
      dp.d[4 + b] = (b < 3) ? i_slot[b] : nullptr;
    }
    scaleall2_k<<<dim3(1024, 8), 256, 0, stream>>>(l2nU, l2nI, colsums, dp);
  } else {
    if (bfI)
      for (int b = 0; b < 4; b++)
        conv_k<<<512, 256, 0, stream>>>(ii[b], itemB + (size_t)b * NI * DD, NI * DD / 4);
    if (bfU)
      for (int b = 0; b < 4; b++)
        conv_k<<<512, 256, 0, stream>>>(uu[b], userB + (size_t)b * NU * DD, NU * DD / 4);
    for (int b0 = 0; b0 < 4; b0 += batchB) {
      bin_k<<<dim3(nchunks, 2, batchB), 512, 0, stream>>>(ep, b0, gcurA, binned);
      sort3_k<<<batchB * (NBU + NBI), 512, 0, stream>>>(rpU, rpI, b0, baseA, binned);
      for (int j = 0; j < batchB; j++) {
        int b = b0 + j;
        const void* xt0 = bfI ? (const void*)(itemB + (size_t)b * NI * DD) : (const void*)ii[b];
        const void* xt1 = bfU ? (const void*)(userB + (size_t)b * NU * DD) : (const void*)uu[b];
        gather_k<<<10000, 256, 0, stream>>>(rpU + (size_t)b * (NU + 1),
                                            binned + ((size_t)j * 2 + 0) * NNZ_E, xt0, bfI ? 1 : 0,
                                            l2nU + (size_t)b * NU * DD, (b < 3) ? u_slot[b] : nullptr, NU);
        gather_k<<<5000, 256, 0, stream>>>(rpI + (size_t)b * (NI + 1),
                                           binned + ((size_t)j * 2 + 1) * NNZ_E, xt1, bfU ? 1 : 0,
                                           l2nI + (size_t)b * NI * DD, (b < 3) ? i_slot[b] : nullptr, NI);
      }
    }
    gemm_sig_k<<<NU / 64, 256, 0, stream>>>(l2nU, (size_t)NU * DD, u_w, user_out, NU);
    gemm_sig_k<<<NI / 64, 256, 0, stream>>>(l2nI, (size_t)NI * DD, i_w, item_out, NI);
    hipMemsetAsync(colsums, 0, NREP * 1024 * 4, stream);
    colsq_k<<<dim3(512, 4), 256, 0, stream>>>(l2nU, (size_t)NU * DD, NU, colsums);
    colsq_k<<<dim3(512, 4), 256, 0, stream>>>(l2nI, (size_t)NI * DD, NI, colsums + 4 * DD);
    inv_k<<<4, 256, 0, stream>>>(colsums, invs, 8 * DD, 1);
    scaleall_k<<<dim3(1024, 8), 256, 0, stream>>>(l2nU, l2nI, invs);
  }
}